// Round 16
// baseline (363.240 us; speedup 1.0000x reference)
//
#include <hip/hip_runtime.h>
#include <hip/hip_bf16.h>
#include <hip/hip_cooperative_groups.h>

#define NPTS   16384
#define PPC    2048
#define DINF   128
#define KNB    32
#define HID    256
#define DOUTF  256

typedef __bf16 bf16x8 __attribute__((ext_vector_type(8)));
typedef __bf16 bf16x4 __attribute__((ext_vector_type(4)));
typedef float  f32x4  __attribute__((ext_vector_type(4)));

// ---- ws layout (bytes) ----
// [0,       1048576) : neighbor idx  ushort [NPTS][32]  (cloud-local j)
// [1048576, 1064960) : neighbor cnt  uchar  [NPTS]
// [1064960, 1146880) : W1 swizzled   bf16   [5][16][64][8]
// [1146880, 1277952) : W2 swizzled   bf16   [8][16][64][8]
// [1277952, 5472256) : x bf16 [NPTS][128]
#define WS_XBF_OFF   1277952
#define WS_XBF_END   5472256

#define MSG_STRIDE 168   // halves; 131 used + zero pad to 160 (validated)
#define HST        264   // halves; 256 used + 8 pad (validated)

static __device__ __forceinline__ unsigned short bf16bits(float f) {
    __hip_bfloat16 h = __float2bfloat16(f);
    return *reinterpret_cast<unsigned short*>(&h);
}

// ---------------------------------------------------------------------------
// aux unit body (validated R19-R29): one 512-thread unit, gid in [0,340992).
// ---------------------------------------------------------------------------
static __device__ __forceinline__ void aux_unit(
    int gid, const float* __restrict__ W1, const float* __restrict__ W2,
    const float* __restrict__ pos, const float* __restrict__ x,
    unsigned short* __restrict__ w1s, unsigned short* __restrict__ w2s,
    unsigned short* __restrict__ xbf,
    float* __restrict__ outpos, float* __restrict__ outbat,
    int do_tail, int do_xbf)
{
    if (gid < 5 * 1024) {
        const int ks = gid >> 10, rem = gid & 1023, nt = rem >> 6, lane = rem & 63;
        const int n  = nt * 16 + (lane & 15);
        const int k0 = ks * 32 + ((lane >> 4) * 8);
        unsigned int u[4];
        #pragma unroll
        for (int q = 0; q < 4; ++q) {
            const int ka = k0 + 2 * q, kb = ka + 1;
            const unsigned int lo = (ka < 131) ? (unsigned int)bf16bits(W1[(size_t)ka * HID + n]) : 0u;
            const unsigned int hi = (kb < 131) ? (unsigned int)bf16bits(W1[(size_t)kb * HID + n]) : 0u;
            u[q] = lo | (hi << 16);
        }
        reinterpret_cast<uint4*>(w1s)[gid] = make_uint4(u[0], u[1], u[2], u[3]);
    } else if (gid < 13312) {
        const int t  = gid - 5120;
        const int ks = t >> 10, rem = t & 1023, nt = rem >> 6, lane = rem & 63;
        const int n  = nt * 16 + (lane & 15);
        const int k0 = ks * 32 + ((lane >> 4) * 8);
        unsigned int u[4];
        #pragma unroll
        for (int q = 0; q < 4; ++q) {
            const unsigned int lo = (unsigned int)bf16bits(W2[(size_t)(k0 + 2 * q) * DOUTF + n]);
            const unsigned int hi = (unsigned int)bf16bits(W2[(size_t)(k0 + 2 * q + 1) * DOUTF + n]);
            u[q] = lo | (hi << 16);
        }
        reinterpret_cast<uint4*>(w2s)[t] = make_uint4(u[0], u[1], u[2], u[3]);
    } else if (gid < 13312 + NPTS * 3) {
        if (do_tail) { const int t = gid - 13312; outpos[t] = pos[t]; }
    } else if (gid < 13312 + NPTS * 3 + NPTS) {
        if (do_tail) { const int t = gid - (13312 + NPTS * 3); outbat[t] = (float)(t >> 11); }
    } else {
        const int t = gid - (13312 + NPTS * 3 + NPTS);       // 0..262143
        if (do_xbf && t < NPTS * DINF / 8) {
            const float4 a = reinterpret_cast<const float4*>(x)[t * 2];
            const float4 b = reinterpret_cast<const float4*>(x)[t * 2 + 1];
            uint4 v;
            v.x = (unsigned int)bf16bits(a.x) | ((unsigned int)bf16bits(a.y) << 16);
            v.y = (unsigned int)bf16bits(a.z) | ((unsigned int)bf16bits(a.w) << 16);
            v.z = (unsigned int)bf16bits(b.x) | ((unsigned int)bf16bits(b.y) << 16);
            v.w = (unsigned int)bf16bits(b.z) | ((unsigned int)bf16bits(b.w) << 16);
            reinterpret_cast<uint4*>(xbf)[t] = v;
        }
    }
}

// ---------------------------------------------------------------------------
// FUSED cooperative kernel (R30): 512 blocks (exactly 2/CU co-resident).
// Phase A: neigh (blocks 0..255, R13-validated) + aux (blocks 256..511,
// <=3 units each). grid.sync(). Phase B: grid-stride over 4096 sa tiles,
// 8/block; tile body BYTE-IDENTICAL to the R26/R29 champion sa (wf1/bb/myc
// reloaded per tile -> register profile = champion's, no persistent state).
// LDS union'd: neigh 66KB fits inside sa's 76.8KB buffer.
// ---------------------------------------------------------------------------
template <int XBF>
__global__ __launch_bounds__(512, 4) void fused_kernel(
    const float* __restrict__ x,
    const float* __restrict__ pos,
    const float* __restrict__ W1, const float* __restrict__ W2,
    unsigned short* __restrict__ idx,
    unsigned char* __restrict__ cnt,
    unsigned short* __restrict__ w1s, unsigned short* __restrict__ w2s,
    unsigned short* __restrict__ xbf,
    const float* __restrict__ b1, const float* __restrict__ b2,
    float* __restrict__ out, float* __restrict__ outpos,
    float* __restrict__ outbat, int do_tail)
{
    __shared__ __align__(16) char smem[76800];

    const int tid = threadIdx.x;

    // ================= Phase A: pre =================
    if (blockIdx.x < 256) {
        float4* sp = reinterpret_cast<float4*>(smem);                                   // 32 KB
        unsigned short (*lists)[64][KNB] =
            reinterpret_cast<unsigned short(*)[64][KNB]>(smem + 32768);                 // 32 KB
        unsigned char (*scnt)[64] = reinterpret_cast<unsigned char(*)[64]>(smem + 65536);

        const int p0  = blockIdx.x * 64;
        const int cb  = (p0 / PPC) * PPC;

        for (int t = tid; t < PPC; t += 512) {
            const float xx = pos[(size_t)(cb + t) * 3 + 0];
            const float yy = pos[(size_t)(cb + t) * 3 + 1];
            const float zz = pos[(size_t)(cb + t) * 3 + 2];
            const float n2 = __fadd_rn(__fadd_rn(__fmul_rn(xx, xx), __fmul_rn(yy, yy)), __fmul_rn(zz, zz));
            sp[t] = make_float4(xx, yy, zz, n2);
        }
        __syncthreads();

        const int seg = tid >> 6;                 // 0..7
        const int p   = tid & 63;
        const float4 pi = sp[p0 - cb + p];

        int c = 0;
        const int jb = seg * (PPC / 8);
        for (int jj = 0; jj < PPC / 8; ++jj) {
            const int j = jb + jj;
            const float4 pj = sp[j];
            const float dot = __fadd_rn(__fadd_rn(__fmul_rn(pi.z, pj.z), __fmul_rn(pi.y, pj.y)),
                                        __fmul_rn(pi.x, pj.x));   // descending (R13-validated)
            const float d2  = __fsub_rn(__fadd_rn(pi.w, pj.w), __fmul_rn(2.0f, dot));
            if (d2 <= 0.04f && c < KNB) { lists[seg][p][c] = (unsigned short)j; ++c; }
        }
        scnt[seg][p] = (unsigned char)c;
        __syncthreads();

        if (tid < 64) {
            const int point = p0 + tid;
            unsigned short* op = idx + (size_t)point * KNB;
            int k = 0;
            for (int s = 0; s < 8; ++s) {
                const int cc = scnt[s][tid];
                for (int r = 0; r < cc && k < KNB; ++r) op[k++] = lists[s][tid][r];
            }
            cnt[point] = (unsigned char)k;
            for (; k < KNB; ++k) op[k] = 0;
        }
    } else {
        const int bb = blockIdx.x - 256;          // 0..255
        aux_unit(bb * 512 + tid,           W1, W2, pos, x, w1s, w2s, xbf, outpos, outbat, do_tail, XBF);
        aux_unit((bb + 256) * 512 + tid,   W1, W2, pos, x, w1s, w2s, xbf, outpos, outbat, do_tail, XBF);
        if (bb < 154)
            aux_unit((bb + 512) * 512 + tid, W1, W2, pos, x, w1s, w2s, xbf, outpos, outbat, do_tail, XBF);
    }

    cooperative_groups::this_grid().sync();

    // ================= Phase B: sa, 8 tiles/block =================
    unsigned short* msg = reinterpret_cast<unsigned short*>(smem);          // 43 KB
    __bf16* hsh = reinterpret_cast<__bf16*>(smem + 43008);                  // 33.8 KB

    const int w    = tid >> 6;                      // wave owns cols [w*32,w*32+32)
    const int lane = tid & 63;
    const int quad = lane >> 4;
    const int l15  = lane & 15;
    const f32x4 fz = {0.f, 0.f, 0.f, 0.f};

    for (int tile = blockIdx.x; tile < NPTS / 4; tile += 512) {
        const int pbase = tile * 4;
        const int cb    = (pbase >> 11) << 11;      // all 4 points same cloud

        // ---- gather: msg[row][0..127]=bf16(x_j), [128..130]=rel, [131..159]=0
        #pragma unroll
        for (int it = 0; it < 4; ++it) {
            const int task  = it * 512 + tid;       // 0..2047
            const int r     = task >> 4;            // row 0..127
            const int sg    = task & 15;            // 8-elem segment
            const int point = pbase + (r >> 5);
            const int slot  = r & 31;
            const int j     = idx[point * KNB + slot];
            uint4 v;
            if (XBF) {
                v = *reinterpret_cast<const uint4*>(xbf + (size_t)(cb + j) * DINF + sg * 8);
            } else {
                const float* xf = x + (size_t)(cb + j) * DINF + sg * 8;
                const float4 pa = reinterpret_cast<const float4*>(xf)[0];
                const float4 pb = reinterpret_cast<const float4*>(xf)[1];
                v.x = (unsigned int)bf16bits(pa.x) | ((unsigned int)bf16bits(pa.y) << 16);
                v.y = (unsigned int)bf16bits(pa.z) | ((unsigned int)bf16bits(pa.w) << 16);
                v.z = (unsigned int)bf16bits(pb.x) | ((unsigned int)bf16bits(pb.y) << 16);
                v.w = (unsigned int)bf16bits(pb.z) | ((unsigned int)bf16bits(pb.w) << 16);
            }
            *reinterpret_cast<uint4*>(&msg[r * MSG_STRIDE + sg * 8]) = v;
        }
        if (tid < 128) {
            const int r     = tid;
            const int point = pbase + (r >> 5);
            const int slot  = r & 31;
            const int j     = idx[point * KNB + slot];
            const float rx = pos[(size_t)(cb + j) * 3 + 0] - pos[(size_t)point * 3 + 0];
            const float ry = pos[(size_t)(cb + j) * 3 + 1] - pos[(size_t)point * 3 + 1];
            const float rz = pos[(size_t)(cb + j) * 3 + 2] - pos[(size_t)point * 3 + 2];
            uint4 vr;
            vr.x = (unsigned int)bf16bits(rx) | ((unsigned int)bf16bits(ry) << 16);
            vr.y = (unsigned int)bf16bits(rz);
            vr.z = 0u; vr.w = 0u;
            const uint4 z = make_uint4(0u, 0u, 0u, 0u);
            *reinterpret_cast<uint4*>(&msg[r * MSG_STRIDE + 128]) = vr;
            *reinterpret_cast<uint4*>(&msg[r * MSG_STRIDE + 136]) = z;
            *reinterpret_cast<uint4*>(&msg[r * MSG_STRIDE + 144]) = z;
            *reinterpret_cast<uint4*>(&msg[r * MSG_STRIDE + 152]) = z;
        }

        // ---- W1 B-frags + biases (reloaded per tile: keeps champion's
        // register profile; L1-hot, ~negligible cost)
        bf16x8 wf1[5][2];
        #pragma unroll
        for (int ks = 0; ks < 5; ++ks)
            #pragma unroll
            for (int nt = 0; nt < 2; ++nt)
                wf1[ks][nt] = *reinterpret_cast<const bf16x8*>(
                    w1s + (size_t)((ks * 16 + (w * 2 + nt)) * 64 + lane) * 8);
        float bb1[2][4];
        #pragma unroll
        for (int nt = 0; nt < 2; ++nt) {
            const float4 bv = *reinterpret_cast<const float4*>(b1 + (w * 2 + nt) * 16 + quad * 4);
            bb1[nt][0] = bv.x; bb1[nt][1] = bv.y; bb1[nt][2] = bv.z; bb1[nt][3] = bv.w;
        }
        float bb2[2];
        #pragma unroll
        for (int nt = 0; nt < 2; ++nt) bb2[nt] = b2[(w * 2 + nt) * 16 + l15];
        int myc[4];
        #pragma unroll
        for (int p = 0; p < 4; ++p) {
            int c = cnt[pbase + p];
            myc[p] = (c > KNB) ? KNB : c;
        }
        __syncthreads();   // gather done

        for (int ph = 0; ph < 2; ++ph) {
            // ---- layer 1 (half)
            #pragma unroll
            for (int mt = 0; mt < 4; ++mt) {
                f32x4 a1[2] = {fz, fz};
                #pragma unroll
                for (int ks = 0; ks < 5; ++ks) {
                    const bf16x8 av = *reinterpret_cast<const bf16x8*>(
                        msg + ((ph * 4 + mt) * 16 + l15) * MSG_STRIDE + ks * 32 + quad * 8);
                    #pragma unroll
                    for (int nt = 0; nt < 2; ++nt)
                        a1[nt] = __builtin_amdgcn_mfma_f32_16x16x32_bf16(wf1[ks][nt], av, a1[nt], 0, 0, 0);
                }
                #pragma unroll
                for (int nt = 0; nt < 2; ++nt) {
                    bf16x4 hv4;
                    #pragma unroll
                    for (int rg = 0; rg < 4; ++rg)
                        hv4[rg] = (__bf16)fmaxf(a1[nt][rg] + bb1[nt][rg], 0.f);
                    *reinterpret_cast<bf16x4*>(
                        &hsh[(mt * 16 + l15) * HST + (w * 2 + nt) * 16 + quad * 4]) = hv4;
                }
            }
            __syncthreads();   // h writes -> h reads

            // ---- layer 2 (half)
            f32x4 acc2[4][2];
            #pragma unroll
            for (int mt = 0; mt < 4; ++mt)
                #pragma unroll
                for (int nt = 0; nt < 2; ++nt) acc2[mt][nt] = fz;

            #pragma unroll
            for (int ks = 0; ks < 8; ++ks) {
                bf16x8 wf2[2];
                #pragma unroll
                for (int nt = 0; nt < 2; ++nt)
                    wf2[nt] = *reinterpret_cast<const bf16x8*>(
                        w2s + (size_t)((ks * 16 + (w * 2 + nt)) * 64 + lane) * 8);
                #pragma unroll
                for (int mt = 0; mt < 4; ++mt) {
                    const bf16x8 hv = *reinterpret_cast<const bf16x8*>(
                        hsh + (mt * 16 + l15) * HST + ks * 32 + quad * 8);
                    #pragma unroll
                    for (int nt = 0; nt < 2; ++nt)
                        acc2[mt][nt] = __builtin_amdgcn_mfma_f32_16x16x32_bf16(hv, wf2[nt], acc2[mt][nt], 0, 0, 0);
                }
            }

            // ---- epilogue (half)
            #pragma unroll
            for (int nt = 0; nt < 2; ++nt) {
                const int col = (w * 2 + nt) * 16 + l15;
                const float bv = bb2[nt];
                #pragma unroll
                for (int p = 0; p < 2; ++p) {
                    const int point = pbase + ph * 2 + p;
                    const int mc = myc[ph * 2 + p];
                    float m = 0.f;                   // post-relu >= 0; self valid
                    #pragma unroll
                    for (int hh = 0; hh < 2; ++hh) {
                        const int mt = 2 * p + hh;
                        #pragma unroll
                        for (int rg = 0; rg < 4; ++rg) {
                            const int slot = hh * 16 + quad * 4 + rg;
                            const float v = fmaxf(acc2[mt][nt][rg] + bv, 0.f);
                            if (slot < mc) m = fmaxf(m, v);
                        }
                    }
                    m = fmaxf(m, __shfl_xor(m, 16, 64));
                    m = fmaxf(m, __shfl_xor(m, 32, 64));
                    if (lane < 16) out[(size_t)point * DOUTF + col] = m;
                }
            }
            __syncthreads();   // hsh reads done; msg safe to overwrite next tile
        }
    }
}

// ---------------------------------------------------------------------------
// Fallback two-launch path (R26/R29 champion, validated 203.7-204.5us).
// ---------------------------------------------------------------------------
__global__ __launch_bounds__(512) void pre_kernel(
    const float* __restrict__ pos,
    const float* __restrict__ x,
    const float* __restrict__ W1, const float* __restrict__ W2,
    unsigned short* __restrict__ idx,
    unsigned char* __restrict__ cnt,
    unsigned short* __restrict__ w1s, unsigned short* __restrict__ w2s,
    unsigned short* __restrict__ xbf,
    float* __restrict__ outpos, float* __restrict__ outbat,
    int do_tail, int do_xbf)
{
    __shared__ __align__(16) float4 sp[PPC];
    __shared__ unsigned short lists[8][64][KNB];
    __shared__ unsigned char  scnt[8][64];

    const int tid = threadIdx.x;

    if (blockIdx.x < 256) {
        const int p0  = blockIdx.x * 64;
        const int cb  = (p0 / PPC) * PPC;

        for (int t = tid; t < PPC; t += 512) {
            const float xx = pos[(size_t)(cb + t) * 3 + 0];
            const float yy = pos[(size_t)(cb + t) * 3 + 1];
            const float zz = pos[(size_t)(cb + t) * 3 + 2];
            const float n2 = __fadd_rn(__fadd_rn(__fmul_rn(xx, xx), __fmul_rn(yy, yy)), __fmul_rn(zz, zz));
            sp[t] = make_float4(xx, yy, zz, n2);
        }
        __syncthreads();

        const int seg = tid >> 6;
        const int p   = tid & 63;
        const float4 pi = sp[p0 - cb + p];

        int c = 0;
        const int jb = seg * (PPC / 8);
        for (int jj = 0; jj < PPC / 8; ++jj) {
            const int j = jb + jj;
            const float4 pj = sp[j];
            const float dot = __fadd_rn(__fadd_rn(__fmul_rn(pi.z, pj.z), __fmul_rn(pi.y, pj.y)),
                                        __fmul_rn(pi.x, pj.x));
            const float d2  = __fsub_rn(__fadd_rn(pi.w, pj.w), __fmul_rn(2.0f, dot));
            if (d2 <= 0.04f && c < KNB) { lists[seg][p][c] = (unsigned short)j; ++c; }
        }
        scnt[seg][p] = (unsigned char)c;
        __syncthreads();

        if (tid < 64) {
            const int point = p0 + tid;
            unsigned short* op = idx + (size_t)point * KNB;
            int k = 0;
            for (int s = 0; s < 8; ++s) {
                const int cc = scnt[s][tid];
                for (int r = 0; r < cc && k < KNB; ++r) op[k++] = lists[s][tid][r];
            }
            cnt[point] = (unsigned char)k;
            for (; k < KNB; ++k) op[k] = 0;
        }
        return;
    }

    aux_unit((blockIdx.x - 256) * 512 + tid, W1, W2, pos, x, w1s, w2s, xbf,
             outpos, outbat, do_tail, do_xbf);
}

template <int XBF>
__global__ __launch_bounds__(512, 4) void sa_kernel_t(
    const float* __restrict__ x,
    const unsigned short* __restrict__ xbf,
    const float* __restrict__ pos,
    const unsigned short* __restrict__ idx,
    const unsigned char*  __restrict__ cnt,
    const unsigned short* __restrict__ w1s,
    const unsigned short* __restrict__ w2s,
    const float* __restrict__ b1,
    const float* __restrict__ b2,
    float* __restrict__ out)
{
    __shared__ __align__(16) unsigned short msg[128 * MSG_STRIDE];
    __shared__ __align__(16) __bf16 hsh[64 * HST];

    const int tid   = threadIdx.x;
    const int pbase = blockIdx.x * 4;
    const int cb    = (pbase >> 11) << 11;

    #pragma unroll
    for (int it = 0; it < 4; ++it) {
        const int task  = it * 512 + tid;
        const int r     = task >> 4;
        const int sg    = task & 15;
        const int point = pbase + (r >> 5);
        const int slot  = r & 31;
        const int j     = idx[point * KNB + slot];
        uint4 v;
        if (XBF) {
            v = *reinterpret_cast<const uint4*>(xbf + (size_t)(cb + j) * DINF + sg * 8);
        } else {
            const float* xf = x + (size_t)(cb + j) * DINF + sg * 8;
            const float4 pa = reinterpret_cast<const float4*>(xf)[0];
            const float4 pb = reinterpret_cast<const float4*>(xf)[1];
            v.x = (unsigned int)bf16bits(pa.x) | ((unsigned int)bf16bits(pa.y) << 16);
            v.y = (unsigned int)bf16bits(pa.z) | ((unsigned int)bf16bits(pa.w) << 16);
            v.z = (unsigned int)bf16bits(pb.x) | ((unsigned int)bf16bits(pb.y) << 16);
            v.w = (unsigned int)bf16bits(pb.z) | ((unsigned int)bf16bits(pb.w) << 16);
        }
        *reinterpret_cast<uint4*>(&msg[r * MSG_STRIDE + sg * 8]) = v;
    }
    if (tid < 128) {
        const int r     = tid;
        const int point = pbase + (r >> 5);
        const int slot  = r & 31;
        const int j     = idx[point * KNB + slot];
        const float rx = pos[(size_t)(cb + j) * 3 + 0] - pos[(size_t)point * 3 + 0];
        const float ry = pos[(size_t)(cb + j) * 3 + 1] - pos[(size_t)point * 3 + 1];
        const float rz = pos[(size_t)(cb + j) * 3 + 2] - pos[(size_t)point * 3 + 2];
        uint4 vr;
        vr.x = (unsigned int)bf16bits(rx) | ((unsigned int)bf16bits(ry) << 16);
        vr.y = (unsigned int)bf16bits(rz);
        vr.z = 0u; vr.w = 0u;
        const uint4 z = make_uint4(0u, 0u, 0u, 0u);
        *reinterpret_cast<uint4*>(&msg[r * MSG_STRIDE + 128]) = vr;
        *reinterpret_cast<uint4*>(&msg[r * MSG_STRIDE + 136]) = z;
        *reinterpret_cast<uint4*>(&msg[r * MSG_STRIDE + 144]) = z;
        *reinterpret_cast<uint4*>(&msg[r * MSG_STRIDE + 152]) = z;
    }

    const int w    = tid >> 6;
    const int lane = tid & 63;
    const int quad = lane >> 4;
    const int l15  = lane & 15;

    bf16x8 wf1[5][2];
    #pragma unroll
    for (int ks = 0; ks < 5; ++ks)
        #pragma unroll
        for (int nt = 0; nt < 2; ++nt)
            wf1[ks][nt] = *reinterpret_cast<const bf16x8*>(
                w1s + (size_t)((ks * 16 + (w * 2 + nt)) * 64 + lane) * 8);
    float bb1[2][4];
    #pragma unroll
    for (int nt = 0; nt < 2; ++nt) {
        const float4 bv = *reinterpret_cast<const float4*>(b1 + (w * 2 + nt) * 16 + quad * 4);
        bb1[nt][0] = bv.x; bb1[nt][1] = bv.y; bb1[nt][2] = bv.z; bb1[nt][3] = bv.w;
    }
    float bb2[2];
    #pragma unroll
    for (int nt = 0; nt < 2; ++nt) bb2[nt] = b2[(w * 2 + nt) * 16 + l15];
    int myc[4];
    #pragma unroll
    for (int p = 0; p < 4; ++p) {
        int c = cnt[pbase + p];
        myc[p] = (c > KNB) ? KNB : c;
    }
    __syncthreads();

    const f32x4 fz = {0.f, 0.f, 0.f, 0.f};

    for (int ph = 0; ph < 2; ++ph) {
        #pragma unroll
        for (int mt = 0; mt < 4; ++mt) {
            f32x4 a1[2] = {fz, fz};
            #pragma unroll
            for (int ks = 0; ks < 5; ++ks) {
                const bf16x8 av = *reinterpret_cast<const bf16x8*>(
                    msg + ((ph * 4 + mt) * 16 + l15) * MSG_STRIDE + ks * 32 + quad * 8);
                #pragma unroll
                for (int nt = 0; nt < 2; ++nt)
                    a1[nt] = __builtin_amdgcn_mfma_f32_16x16x32_bf16(wf1[ks][nt], av, a1[nt], 0, 0, 0);
            }
            #pragma unroll
            for (int nt = 0; nt < 2; ++nt) {
                bf16x4 hv4;
                #pragma unroll
                for (int rg = 0; rg < 4; ++rg)
                    hv4[rg] = (__bf16)fmaxf(a1[nt][rg] + bb1[nt][rg], 0.f);
                *reinterpret_cast<bf16x4*>(
                    &hsh[(mt * 16 + l15) * HST + (w * 2 + nt) * 16 + quad * 4]) = hv4;
            }
        }
        __syncthreads();

        f32x4 acc2[4][2];
        #pragma unroll
        for (int mt = 0; mt < 4; ++mt)
            #pragma unroll
            for (int nt = 0; nt < 2; ++nt) acc2[mt][nt] = fz;

        #pragma unroll
        for (int ks = 0; ks < 8; ++ks) {
            bf16x8 wf2[2];
            #pragma unroll
            for (int nt = 0; nt < 2; ++nt)
                wf2[nt] = *reinterpret_cast<const bf16x8*>(
                    w2s + (size_t)((ks * 16 + (w * 2 + nt)) * 64 + lane) * 8);
            #pragma unroll
            for (int mt = 0; mt < 4; ++mt) {
                const bf16x8 hv = *reinterpret_cast<const bf16x8*>(
                    hsh + (mt * 16 + l15) * HST + ks * 32 + quad * 8);
                #pragma unroll
                for (int nt = 0; nt < 2; ++nt)
                    acc2[mt][nt] = __builtin_amdgcn_mfma_f32_16x16x32_bf16(hv, wf2[nt], acc2[mt][nt], 0, 0, 0);
            }
        }

        #pragma unroll
        for (int nt = 0; nt < 2; ++nt) {
            const int col = (w * 2 + nt) * 16 + l15;
            const float bv = bb2[nt];
            #pragma unroll
            for (int p = 0; p < 2; ++p) {
                const int point = pbase + ph * 2 + p;
                const int mc = myc[ph * 2 + p];
                float m = 0.f;
                #pragma unroll
                for (int hh = 0; hh < 2; ++hh) {
                    const int mt = 2 * p + hh;
                    #pragma unroll
                    for (int rg = 0; rg < 4; ++rg) {
                        const int slot = hh * 16 + quad * 4 + rg;
                        const float v = fmaxf(acc2[mt][nt][rg] + bv, 0.f);
                        if (slot < mc) m = fmaxf(m, v);
                    }
                }
                m = fmaxf(m, __shfl_xor(m, 16, 64));
                m = fmaxf(m, __shfl_xor(m, 32, 64));
                if (lane < 16) out[(size_t)point * DOUTF + col] = m;
            }
        }
        __syncthreads();
    }
}

extern "C" void kernel_launch(void* const* d_in, const int* in_sizes, int n_in,
                              void* d_out, int out_size, void* d_ws, size_t ws_size,
                              hipStream_t stream)
{
    const float *x = nullptr, *pos = nullptr, *W1 = nullptr, *W2 = nullptr;
    const float *b1 = nullptr, *b2 = nullptr;
    int nbias = 0;
    for (int i = 0; i < n_in && i < 16; ++i) {
        switch (in_sizes[i]) {
            case NPTS * DINF: x   = (const float*)d_in[i]; break;
            case NPTS * 3:    pos = (const float*)d_in[i]; break;
            case 131 * HID:   W1  = (const float*)d_in[i]; break;
            case HID * DOUTF: W2  = (const float*)d_in[i]; break;
            case 256:         if (nbias == 0) b1 = (const float*)d_in[i];
                              else            b2 = (const float*)d_in[i];
                              ++nbias; break;
            default: break;   // batch (unused; structurally i>>11)
        }
    }
    if (!x)   x   = (const float*)d_in[0];
    if (!pos) pos = (const float*)d_in[1];
    if (!W1)  W1  = (const float*)d_in[3];
    if (!b1)  b1  = (const float*)d_in[4];
    if (!W2)  W2  = (const float*)d_in[5];
    if (!b2)  b2  = (const float*)d_in[6];

    char* ws = (char*)d_ws;
    unsigned short* idx = (unsigned short*)(ws + 0);
    unsigned char*  cnt = (unsigned char*)(ws + 1048576);
    unsigned short* w1s = (unsigned short*)(ws + 1064960);
    unsigned short* w2s = (unsigned short*)(ws + 1146880);
    unsigned short* xbf = (unsigned short*)(ws + WS_XBF_OFF);

    const int use_xbf = (ws_size >= (size_t)WS_XBF_END) ? 1 : 0;
    const int do_tail = (out_size >= NPTS * DOUTF + NPTS * 3 + NPTS) ? 1 : 0;

    float* out    = (float*)d_out;
    float* outpos = out + (size_t)NPTS * DOUTF;
    float* outbat = outpos + (size_t)NPTS * 3;

    // ---- preferred: single cooperative launch (removes the pre->sa
    // launch boundary, ~8-10us). Clean fallback if unsupported.
    static int coop_attr = -1;
    if (coop_attr < 0) {
        int v = 0;
        if (hipDeviceGetAttribute(&v, hipDeviceAttributeCooperativeLaunch, 0) != hipSuccess) v = 0;
        coop_attr = v;
    }

    bool launched = false;
    if (coop_attr == 1) {
        int do_tail_v = do_tail;
        void* args[] = {
            (void*)&x, (void*)&pos, (void*)&W1, (void*)&W2,
            (void*)&idx, (void*)&cnt, (void*)&w1s, (void*)&w2s, (void*)&xbf,
            (void*)&b1, (void*)&b2,
            (void*)&out, (void*)&outpos, (void*)&outbat, (void*)&do_tail_v
        };
        const void* fn = use_xbf ? (const void*)fused_kernel<1>
                                 : (const void*)fused_kernel<0>;
        hipError_t e = hipLaunchCooperativeKernel(fn, dim3(512), dim3(512), args, 0, stream);
        if (e == hipSuccess) launched = true;
        else (void)hipGetLastError();   // clear error state, fall back
    }

    if (!launched) {
        hipLaunchKernelGGL(pre_kernel, dim3(256 + 666), dim3(512), 0, stream,
                           pos, x, W1, W2, idx, cnt, w1s, w2s, xbf,
                           outpos, outbat, do_tail, use_xbf);
        if (use_xbf) {
            hipLaunchKernelGGL((sa_kernel_t<1>), dim3(NPTS / 4), dim3(512), 0, stream,
                               x, xbf, pos, idx, cnt, w1s, w2s, b1, b2, out);
        } else {
            hipLaunchKernelGGL((sa_kernel_t<0>), dim3(NPTS / 4), dim3(512), 0, stream,
                               x, xbf, pos, idx, cnt, w1s, w2s, b1, b2, out);
        }
    }
}

// Round 17
// 204.438 us; speedup vs baseline: 1.7768x; 1.7768x over previous
//
#include <hip/hip_runtime.h>
#include <hip/hip_bf16.h>

#define NPTS   16384
#define PPC    2048
#define DINF   128
#define KNB    32
#define HID    256
#define DOUTF  256

typedef __bf16 bf16x8 __attribute__((ext_vector_type(8)));
typedef __bf16 bf16x4 __attribute__((ext_vector_type(4)));
typedef float  f32x4  __attribute__((ext_vector_type(4)));

// ---- ws layout (bytes) ----
// [0,       1048576) : neighbor idx  ushort [NPTS][32]  (cloud-local j)
// [1048576, 1064960) : neighbor cnt  uchar  [NPTS]
// [1064960, 1146880) : W1 swizzled   bf16   [5][16][64][8]
// [1146880, 1277952) : W2 swizzled   bf16   [8][16][64][8]
// [1277952, 5472256) : x bf16 [NPTS][128]
#define WS_XBF_OFF   1277952
#define WS_XBF_END   5472256

static __device__ __forceinline__ unsigned short bf16bits(float f) {
    __hip_bfloat16 h = __float2bfloat16(f);
    return *reinterpret_cast<unsigned short*>(&h);
}

// ---------------------------------------------------------------------------
// Kernel 1 (R26 champion, validated): FUSED pre-kernel = ball-query
// (blocks 0..255) + aux (blocks 256..921). R30's cooperative single-launch
// fusion regressed (allocator live-range union spilled + grid-stride tile
// loop broke L2 locality) — two launches is the measured optimum.
// ---------------------------------------------------------------------------
__global__ __launch_bounds__(512) void pre_kernel(
    const float* __restrict__ pos,
    const float* __restrict__ x,
    const float* __restrict__ W1, const float* __restrict__ W2,
    unsigned short* __restrict__ idx,
    unsigned char* __restrict__ cnt,
    unsigned short* __restrict__ w1s, unsigned short* __restrict__ w2s,
    unsigned short* __restrict__ xbf,
    float* __restrict__ outpos, float* __restrict__ outbat,
    int do_tail, int do_xbf)
{
    __shared__ __align__(16) float4 sp[PPC];              // 32 KB
    __shared__ unsigned short lists[8][64][KNB];          // 32 KB
    __shared__ unsigned char  scnt[8][64];

    const int tid = threadIdx.x;

    if (blockIdx.x < 256) {
        // ---- neigh half (R13-validated semantics: descending-dot, no FMA,
        // d2 = (n2i+n2j)-2*dot <= 0.04f, first-32-ascending-index)
        const int p0  = blockIdx.x * 64;
        const int cb  = (p0 / PPC) * PPC;

        for (int t = tid; t < PPC; t += 512) {
            const float xx = pos[(size_t)(cb + t) * 3 + 0];
            const float yy = pos[(size_t)(cb + t) * 3 + 1];
            const float zz = pos[(size_t)(cb + t) * 3 + 2];
            const float n2 = __fadd_rn(__fadd_rn(__fmul_rn(xx, xx), __fmul_rn(yy, yy)), __fmul_rn(zz, zz));
            sp[t] = make_float4(xx, yy, zz, n2);
        }
        __syncthreads();

        const int seg = tid >> 6;                 // 0..7
        const int p   = tid & 63;
        const float4 pi = sp[p0 - cb + p];

        int c = 0;
        const int jb = seg * (PPC / 8);
        for (int jj = 0; jj < PPC / 8; ++jj) {
            const int j = jb + jj;
            const float4 pj = sp[j];
            const float dot = __fadd_rn(__fadd_rn(__fmul_rn(pi.z, pj.z), __fmul_rn(pi.y, pj.y)),
                                        __fmul_rn(pi.x, pj.x));   // descending (R13-validated)
            const float d2  = __fsub_rn(__fadd_rn(pi.w, pj.w), __fmul_rn(2.0f, dot));
            if (d2 <= 0.04f && c < KNB) { lists[seg][p][c] = (unsigned short)j; ++c; }
        }
        scnt[seg][p] = (unsigned char)c;
        __syncthreads();

        if (tid < 64) {
            const int point = p0 + tid;
            unsigned short* op = idx + (size_t)point * KNB;
            int k = 0;
            for (int s = 0; s < 8; ++s) {
                const int cc = scnt[s][tid];
                for (int r = 0; r < cc && k < KNB; ++r) op[k++] = lists[s][tid][r];
            }
            cnt[point] = (unsigned char)k;
            for (; k < KNB; ++k) op[k] = 0;
        }
        return;
    }

    // ---- aux half: gid over [0, 340992)
    const int gid = (blockIdx.x - 256) * 512 + tid;
    if (gid < 5 * 1024) {
        const int ks = gid >> 10, rem = gid & 1023, nt = rem >> 6, lane = rem & 63;
        const int n  = nt * 16 + (lane & 15);
        const int k0 = ks * 32 + ((lane >> 4) * 8);
        unsigned int u[4];
        #pragma unroll
        for (int q = 0; q < 4; ++q) {
            const int ka = k0 + 2 * q, kb = ka + 1;
            const unsigned int lo = (ka < 131) ? (unsigned int)bf16bits(W1[(size_t)ka * HID + n]) : 0u;
            const unsigned int hi = (kb < 131) ? (unsigned int)bf16bits(W1[(size_t)kb * HID + n]) : 0u;
            u[q] = lo | (hi << 16);
        }
        reinterpret_cast<uint4*>(w1s)[gid] = make_uint4(u[0], u[1], u[2], u[3]);
    } else if (gid < 13312) {
        const int t  = gid - 5120;
        const int ks = t >> 10, rem = t & 1023, nt = rem >> 6, lane = rem & 63;
        const int n  = nt * 16 + (lane & 15);
        const int k0 = ks * 32 + ((lane >> 4) * 8);
        unsigned int u[4];
        #pragma unroll
        for (int q = 0; q < 4; ++q) {
            const unsigned int lo = (unsigned int)bf16bits(W2[(size_t)(k0 + 2 * q) * DOUTF + n]);
            const unsigned int hi = (unsigned int)bf16bits(W2[(size_t)(k0 + 2 * q + 1) * DOUTF + n]);
            u[q] = lo | (hi << 16);
        }
        reinterpret_cast<uint4*>(w2s)[t] = make_uint4(u[0], u[1], u[2], u[3]);
    } else if (gid < 13312 + NPTS * 3) {
        if (do_tail) { const int t = gid - 13312; outpos[t] = pos[t]; }
    } else if (gid < 13312 + NPTS * 3 + NPTS) {
        if (do_tail) { const int t = gid - (13312 + NPTS * 3); outbat[t] = (float)(t >> 11); }
    } else {
        const int t = gid - (13312 + NPTS * 3 + NPTS);       // 0..262143
        if (do_xbf && t < NPTS * DINF / 8) {
            const float4 a = reinterpret_cast<const float4*>(x)[t * 2];
            const float4 b = reinterpret_cast<const float4*>(x)[t * 2 + 1];
            uint4 v;
            v.x = (unsigned int)bf16bits(a.x) | ((unsigned int)bf16bits(a.y) << 16);
            v.y = (unsigned int)bf16bits(a.z) | ((unsigned int)bf16bits(a.w) << 16);
            v.z = (unsigned int)bf16bits(b.x) | ((unsigned int)bf16bits(b.y) << 16);
            v.w = (unsigned int)bf16bits(b.z) | ((unsigned int)bf16bits(b.w) << 16);
            reinterpret_cast<uint4*>(xbf)[t] = v;
        }
    }
}

// ---------------------------------------------------------------------------
// Kernel 2 (EXACT R26/R29 champion sa; measured 117.5us sa / 203.7us total,
// absmax 0.0234, 64 VGPR, no scratch). Design space fully explored:
//  - nt=4 col-widening: spilled 4x (R18/R21/R22/R27) — compiler's practical
//    spill threshold ~100 live VGPRs; this shape has ZERO headroom (R28:
//    +8 staged VGPRs -> 152MB scratch).
//  - LDS-shrink for 3 blocks/CU: wrong answer (R23) or spill-by-bound (R22).
//  - 2 points/block for 4 blocks/CU: weight re-streaming regression (R25).
//  - y-hoist (fewer FLOPs): gather-traffic regression (R20).
//  - cooperative single-launch fusion: spill + L2-locality loss (R30).
// This is the stable optimum of this structure.
// ---------------------------------------------------------------------------
#define MSG_STRIDE 168   // halves; 131 used + zero pad to 160 (validated)
#define HST        264   // halves; 256 used + 8 pad (validated)

template <int XBF>
__global__ __launch_bounds__(512, 4) void sa_kernel_t(
    const float* __restrict__ x,
    const unsigned short* __restrict__ xbf,
    const float* __restrict__ pos,
    const unsigned short* __restrict__ idx,
    const unsigned char*  __restrict__ cnt,
    const unsigned short* __restrict__ w1s,
    const unsigned short* __restrict__ w2s,
    const float* __restrict__ b1,
    const float* __restrict__ b2,
    float* __restrict__ out)
{
    __shared__ __align__(16) unsigned short msg[128 * MSG_STRIDE];  // 43 KB
    __shared__ __align__(16) __bf16 hsh[64 * HST];                  // 33.8 KB

    const int tid   = threadIdx.x;
    const int pbase = blockIdx.x * 4;
    const int cb    = (pbase >> 11) << 11;          // all 4 points same cloud

    // ---- gather: msg[row][0..127]=bf16(x_j), [128..130]=rel, [131..159]=0
    #pragma unroll
    for (int it = 0; it < 4; ++it) {
        const int task  = it * 512 + tid;           // 0..2047
        const int r     = task >> 4;                // row 0..127
        const int sg    = task & 15;                // 8-elem segment
        const int point = pbase + (r >> 5);
        const int slot  = r & 31;
        const int j     = idx[point * KNB + slot];
        uint4 v;
        if (XBF) {
            v = *reinterpret_cast<const uint4*>(xbf + (size_t)(cb + j) * DINF + sg * 8);
        } else {
            const float* xf = x + (size_t)(cb + j) * DINF + sg * 8;
            const float4 pa = reinterpret_cast<const float4*>(xf)[0];
            const float4 pb = reinterpret_cast<const float4*>(xf)[1];
            v.x = (unsigned int)bf16bits(pa.x) | ((unsigned int)bf16bits(pa.y) << 16);
            v.y = (unsigned int)bf16bits(pa.z) | ((unsigned int)bf16bits(pa.w) << 16);
            v.z = (unsigned int)bf16bits(pb.x) | ((unsigned int)bf16bits(pb.y) << 16);
            v.w = (unsigned int)bf16bits(pb.z) | ((unsigned int)bf16bits(pb.w) << 16);
        }
        *reinterpret_cast<uint4*>(&msg[r * MSG_STRIDE + sg * 8]) = v;
    }
    if (tid < 128) {
        const int r     = tid;
        const int point = pbase + (r >> 5);
        const int slot  = r & 31;
        const int j     = idx[point * KNB + slot];
        const float rx = pos[(size_t)(cb + j) * 3 + 0] - pos[(size_t)point * 3 + 0];
        const float ry = pos[(size_t)(cb + j) * 3 + 1] - pos[(size_t)point * 3 + 1];
        const float rz = pos[(size_t)(cb + j) * 3 + 2] - pos[(size_t)point * 3 + 2];
        uint4 vr;
        vr.x = (unsigned int)bf16bits(rx) | ((unsigned int)bf16bits(ry) << 16);
        vr.y = (unsigned int)bf16bits(rz);
        vr.z = 0u; vr.w = 0u;
        const uint4 z = make_uint4(0u, 0u, 0u, 0u);
        *reinterpret_cast<uint4*>(&msg[r * MSG_STRIDE + 128]) = vr;
        *reinterpret_cast<uint4*>(&msg[r * MSG_STRIDE + 136]) = z;
        *reinterpret_cast<uint4*>(&msg[r * MSG_STRIDE + 144]) = z;
        *reinterpret_cast<uint4*>(&msg[r * MSG_STRIDE + 152]) = z;
    }

    const int w    = tid >> 6;                      // wave owns cols [w*32,w*32+32)
    const int lane = tid & 63;
    const int quad = lane >> 4;
    const int l15  = lane & 15;

    // ---- W1 B-frags + biases in registers (once, reused both phases)
    bf16x8 wf1[5][2];
    #pragma unroll
    for (int ks = 0; ks < 5; ++ks)
        #pragma unroll
        for (int nt = 0; nt < 2; ++nt)
            wf1[ks][nt] = *reinterpret_cast<const bf16x8*>(
                w1s + (size_t)((ks * 16 + (w * 2 + nt)) * 64 + lane) * 8);
    // swapped-D layout: lane reg rg holds col nbase + quad*4 + rg
    float bb1[2][4];
    #pragma unroll
    for (int nt = 0; nt < 2; ++nt) {
        const float4 bv = *reinterpret_cast<const float4*>(b1 + (w * 2 + nt) * 16 + quad * 4);
        bb1[nt][0] = bv.x; bb1[nt][1] = bv.y; bb1[nt][2] = bv.z; bb1[nt][3] = bv.w;
    }
    float bb2[2];
    #pragma unroll
    for (int nt = 0; nt < 2; ++nt) bb2[nt] = b2[(w * 2 + nt) * 16 + l15];
    int myc[4];
    #pragma unroll
    for (int p = 0; p < 4; ++p) {
        int c = cnt[pbase + p];
        myc[p] = (c > KNB) ? KNB : c;
    }
    __syncthreads();   // gather done

    const f32x4 fz = {0.f, 0.f, 0.f, 0.f};

    for (int ph = 0; ph < 2; ++ph) {
        // ---- layer 1 (half): mt_g = ph*4 + mt, writes hsh rows mt*16+..
        #pragma unroll
        for (int mt = 0; mt < 4; ++mt) {
            f32x4 a1[2] = {fz, fz};
            #pragma unroll
            for (int ks = 0; ks < 5; ++ks) {
                const bf16x8 av = *reinterpret_cast<const bf16x8*>(
                    msg + ((ph * 4 + mt) * 16 + l15) * MSG_STRIDE + ks * 32 + quad * 8);
                #pragma unroll
                for (int nt = 0; nt < 2; ++nt)
                    a1[nt] = __builtin_amdgcn_mfma_f32_16x16x32_bf16(wf1[ks][nt], av, a1[nt], 0, 0, 0);
            }
            // bias+relu+bf16 -> h. D' layout: row(l15)=msg row, reg rg = col quad*4+rg
            #pragma unroll
            for (int nt = 0; nt < 2; ++nt) {
                bf16x4 hv4;
                #pragma unroll
                for (int rg = 0; rg < 4; ++rg)
                    hv4[rg] = (__bf16)fmaxf(a1[nt][rg] + bb1[nt][rg], 0.f);
                *reinterpret_cast<bf16x4*>(
                    &hsh[(mt * 16 + l15) * HST + (w * 2 + nt) * 16 + quad * 4]) = hv4;
            }
        }
        __syncthreads();   // h writes -> h reads

        // ---- layer 2 (half): rows ph*64..ph*64+63, ks-outer
        f32x4 acc2[4][2];
        #pragma unroll
        for (int mt = 0; mt < 4; ++mt)
            #pragma unroll
            for (int nt = 0; nt < 2; ++nt) acc2[mt][nt] = fz;

        #pragma unroll
        for (int ks = 0; ks < 8; ++ks) {
            bf16x8 wf2[2];
            #pragma unroll
            for (int nt = 0; nt < 2; ++nt)
                wf2[nt] = *reinterpret_cast<const bf16x8*>(
                    w2s + (size_t)((ks * 16 + (w * 2 + nt)) * 64 + lane) * 8);
            #pragma unroll
            for (int mt = 0; mt < 4; ++mt) {
                const bf16x8 hv = *reinterpret_cast<const bf16x8*>(
                    hsh + (mt * 16 + l15) * HST + ks * 32 + quad * 8);
                #pragma unroll
                for (int nt = 0; nt < 2; ++nt)
                    acc2[mt][nt] = __builtin_amdgcn_mfma_f32_16x16x32_bf16(hv, wf2[nt], acc2[mt][nt], 0, 0, 0);
            }
        }

        // ---- epilogue (half): points pbase + ph*2 + {0,1}
        #pragma unroll
        for (int nt = 0; nt < 2; ++nt) {
            const int col = (w * 2 + nt) * 16 + l15;
            const float bv = bb2[nt];
            #pragma unroll
            for (int p = 0; p < 2; ++p) {
                const int point = pbase + ph * 2 + p;
                const int mc = myc[ph * 2 + p];
                float m = 0.f;                       // post-relu >= 0; self valid
                #pragma unroll
                for (int hh = 0; hh < 2; ++hh) {
                    const int mt = 2 * p + hh;
                    #pragma unroll
                    for (int rg = 0; rg < 4; ++rg) {
                        const int slot = hh * 16 + quad * 4 + rg;
                        const float v = fmaxf(acc2[mt][nt][rg] + bv, 0.f);
                        if (slot < mc) m = fmaxf(m, v);
                    }
                }
                m = fmaxf(m, __shfl_xor(m, 16, 64));
                m = fmaxf(m, __shfl_xor(m, 32, 64));
                if (lane < 16) out[(size_t)point * DOUTF + col] = m;
            }
        }
        __syncthreads();   // hsh reads done before next phase's writes
    }
}

extern "C" void kernel_launch(void* const* d_in, const int* in_sizes, int n_in,
                              void* d_out, int out_size, void* d_ws, size_t ws_size,
                              hipStream_t stream)
{
    const float *x = nullptr, *pos = nullptr, *W1 = nullptr, *W2 = nullptr;
    const float *b1 = nullptr, *b2 = nullptr;
    int nbias = 0;
    for (int i = 0; i < n_in && i < 16; ++i) {
        switch (in_sizes[i]) {
            case NPTS * DINF: x   = (const float*)d_in[i]; break;
            case NPTS * 3:    pos = (const float*)d_in[i]; break;
            case 131 * HID:   W1  = (const float*)d_in[i]; break;
            case HID * DOUTF: W2  = (const float*)d_in[i]; break;
            case 256:         if (nbias == 0) b1 = (const float*)d_in[i];
                              else            b2 = (const float*)d_in[i];
                              ++nbias; break;
            default: break;   // batch (unused; structurally i>>11)
        }
    }
    if (!x)   x   = (const float*)d_in[0];
    if (!pos) pos = (const float*)d_in[1];
    if (!W1)  W1  = (const float*)d_in[3];
    if (!b1)  b1  = (const float*)d_in[4];
    if (!W2)  W2  = (const float*)d_in[5];
    if (!b2)  b2  = (const float*)d_in[6];

    char* ws = (char*)d_ws;
    unsigned short* idx = (unsigned short*)(ws + 0);
    unsigned char*  cnt = (unsigned char*)(ws + 1048576);
    unsigned short* w1s = (unsigned short*)(ws + 1064960);
    unsigned short* w2s = (unsigned short*)(ws + 1146880);
    unsigned short* xbf = (unsigned short*)(ws + WS_XBF_OFF);

    const int use_xbf = (ws_size >= (size_t)WS_XBF_END) ? 1 : 0;
    const int do_tail = (out_size >= NPTS * DOUTF + NPTS * 3 + NPTS) ? 1 : 0;

    float* out    = (float*)d_out;
    float* outpos = out + (size_t)NPTS * DOUTF;
    float* outbat = outpos + (size_t)NPTS * 3;

    hipLaunchKernelGGL(pre_kernel, dim3(256 + 666), dim3(512), 0, stream,
                       pos, x, W1, W2, idx, cnt, w1s, w2s, xbf,
                       outpos, outbat, do_tail, use_xbf);
    if (use_xbf) {
        hipLaunchKernelGGL((sa_kernel_t<1>), dim3(NPTS / 4), dim3(512), 0, stream,
                           x, xbf, pos, idx, cnt, w1s, w2s, b1, b2, out);
    } else {
        hipLaunchKernelGGL((sa_kernel_t<0>), dim3(NPTS / 4), dim3(512), 0, stream,
                           x, xbf, pos, idx, cnt, w1s, w2s, b1, b2, out);
    }
}

// Round 18
// 203.642 us; speedup vs baseline: 1.7837x; 1.0039x over previous
//
#include <hip/hip_runtime.h>
#include <hip/hip_bf16.h>

#define NPTS   16384
#define PPC    2048
#define DINF   128
#define KNB    32
#define HID    256
#define DOUTF  256

typedef __bf16 bf16x8 __attribute__((ext_vector_type(8)));
typedef __bf16 bf16x4 __attribute__((ext_vector_type(4)));
typedef float  f32x4  __attribute__((ext_vector_type(4)));

// ---- ws layout (bytes) ----
// [0,       1048576) : neighbor idx  ushort [NPTS][32]  (cloud-local j)
// [1048576, 1064960) : neighbor cnt  uchar  [NPTS]
// [1064960, 1146880) : W1 swizzled   bf16   [5][16][64][8]
// [1146880, 1277952) : W2 swizzled   bf16   [8][16][64][8]
// [1277952, 5472256) : x bf16 [NPTS][128]
#define WS_XBF_OFF   1277952
#define WS_XBF_END   5472256

static __device__ __forceinline__ unsigned short bf16bits(float f) {
    __hip_bfloat16 h = __float2bfloat16(f);
    return *reinterpret_cast<unsigned short*>(&h);
}

// ---------------------------------------------------------------------------
// Kernel 1 (R26 champion, validated): FUSED pre-kernel = ball-query
// (blocks 0..255) + aux (blocks 256..921). R30's cooperative single-launch
// fusion regressed (allocator live-range union spilled + grid-stride tile
// loop broke L2 locality) — two launches is the measured optimum.
// ---------------------------------------------------------------------------
__global__ __launch_bounds__(512) void pre_kernel(
    const float* __restrict__ pos,
    const float* __restrict__ x,
    const float* __restrict__ W1, const float* __restrict__ W2,
    unsigned short* __restrict__ idx,
    unsigned char* __restrict__ cnt,
    unsigned short* __restrict__ w1s, unsigned short* __restrict__ w2s,
    unsigned short* __restrict__ xbf,
    float* __restrict__ outpos, float* __restrict__ outbat,
    int do_tail, int do_xbf)
{
    __shared__ __align__(16) float4 sp[PPC];              // 32 KB
    __shared__ unsigned short lists[8][64][KNB];          // 32 KB
    __shared__ unsigned char  scnt[8][64];

    const int tid = threadIdx.x;

    if (blockIdx.x < 256) {
        // ---- neigh half (R13-validated semantics: descending-dot, no FMA,
        // d2 = (n2i+n2j)-2*dot <= 0.04f, first-32-ascending-index)
        const int p0  = blockIdx.x * 64;
        const int cb  = (p0 / PPC) * PPC;

        for (int t = tid; t < PPC; t += 512) {
            const float xx = pos[(size_t)(cb + t) * 3 + 0];
            const float yy = pos[(size_t)(cb + t) * 3 + 1];
            const float zz = pos[(size_t)(cb + t) * 3 + 2];
            const float n2 = __fadd_rn(__fadd_rn(__fmul_rn(xx, xx), __fmul_rn(yy, yy)), __fmul_rn(zz, zz));
            sp[t] = make_float4(xx, yy, zz, n2);
        }
        __syncthreads();

        const int seg = tid >> 6;                 // 0..7
        const int p   = tid & 63;
        const float4 pi = sp[p0 - cb + p];

        int c = 0;
        const int jb = seg * (PPC / 8);
        for (int jj = 0; jj < PPC / 8; ++jj) {
            const int j = jb + jj;
            const float4 pj = sp[j];
            const float dot = __fadd_rn(__fadd_rn(__fmul_rn(pi.z, pj.z), __fmul_rn(pi.y, pj.y)),
                                        __fmul_rn(pi.x, pj.x));   // descending (R13-validated)
            const float d2  = __fsub_rn(__fadd_rn(pi.w, pj.w), __fmul_rn(2.0f, dot));
            if (d2 <= 0.04f && c < KNB) { lists[seg][p][c] = (unsigned short)j; ++c; }
        }
        scnt[seg][p] = (unsigned char)c;
        __syncthreads();

        if (tid < 64) {
            const int point = p0 + tid;
            unsigned short* op = idx + (size_t)point * KNB;
            int k = 0;
            for (int s = 0; s < 8; ++s) {
                const int cc = scnt[s][tid];
                for (int r = 0; r < cc && k < KNB; ++r) op[k++] = lists[s][tid][r];
            }
            cnt[point] = (unsigned char)k;
            for (; k < KNB; ++k) op[k] = 0;
        }
        return;
    }

    // ---- aux half: gid over [0, 340992)
    const int gid = (blockIdx.x - 256) * 512 + tid;
    if (gid < 5 * 1024) {
        const int ks = gid >> 10, rem = gid & 1023, nt = rem >> 6, lane = rem & 63;
        const int n  = nt * 16 + (lane & 15);
        const int k0 = ks * 32 + ((lane >> 4) * 8);
        unsigned int u[4];
        #pragma unroll
        for (int q = 0; q < 4; ++q) {
            const int ka = k0 + 2 * q, kb = ka + 1;
            const unsigned int lo = (ka < 131) ? (unsigned int)bf16bits(W1[(size_t)ka * HID + n]) : 0u;
            const unsigned int hi = (kb < 131) ? (unsigned int)bf16bits(W1[(size_t)kb * HID + n]) : 0u;
            u[q] = lo | (hi << 16);
        }
        reinterpret_cast<uint4*>(w1s)[gid] = make_uint4(u[0], u[1], u[2], u[3]);
    } else if (gid < 13312) {
        const int t  = gid - 5120;
        const int ks = t >> 10, rem = t & 1023, nt = rem >> 6, lane = rem & 63;
        const int n  = nt * 16 + (lane & 15);
        const int k0 = ks * 32 + ((lane >> 4) * 8);
        unsigned int u[4];
        #pragma unroll
        for (int q = 0; q < 4; ++q) {
            const unsigned int lo = (unsigned int)bf16bits(W2[(size_t)(k0 + 2 * q) * DOUTF + n]);
            const unsigned int hi = (unsigned int)bf16bits(W2[(size_t)(k0 + 2 * q + 1) * DOUTF + n]);
            u[q] = lo | (hi << 16);
        }
        reinterpret_cast<uint4*>(w2s)[t] = make_uint4(u[0], u[1], u[2], u[3]);
    } else if (gid < 13312 + NPTS * 3) {
        if (do_tail) { const int t = gid - 13312; outpos[t] = pos[t]; }
    } else if (gid < 13312 + NPTS * 3 + NPTS) {
        if (do_tail) { const int t = gid - (13312 + NPTS * 3); outbat[t] = (float)(t >> 11); }
    } else {
        const int t = gid - (13312 + NPTS * 3 + NPTS);       // 0..262143
        if (do_xbf && t < NPTS * DINF / 8) {
            const float4 a = reinterpret_cast<const float4*>(x)[t * 2];
            const float4 b = reinterpret_cast<const float4*>(x)[t * 2 + 1];
            uint4 v;
            v.x = (unsigned int)bf16bits(a.x) | ((unsigned int)bf16bits(a.y) << 16);
            v.y = (unsigned int)bf16bits(a.z) | ((unsigned int)bf16bits(a.w) << 16);
            v.z = (unsigned int)bf16bits(b.x) | ((unsigned int)bf16bits(b.y) << 16);
            v.w = (unsigned int)bf16bits(b.z) | ((unsigned int)bf16bits(b.w) << 16);
            reinterpret_cast<uint4*>(xbf)[t] = v;
        }
    }
}

// ---------------------------------------------------------------------------
// Kernel 2 (EXACT R26/R29 champion sa; measured 117.5us sa / 203.7us total,
// absmax 0.0234, 64 VGPR, no scratch). Design space fully explored:
//  - nt=4 col-widening: spilled 4x (R18/R21/R22/R27) — compiler's practical
//    spill threshold ~100 live VGPRs; this shape has ZERO headroom (R28:
//    +8 staged VGPRs -> 152MB scratch).
//  - LDS-shrink for 3 blocks/CU: wrong answer (R23) or spill-by-bound (R22).
//  - 2 points/block for 4 blocks/CU: weight re-streaming regression (R25).
//  - y-hoist (fewer FLOPs): gather-traffic regression (R20).
//  - cooperative single-launch fusion: spill + L2-locality loss (R30).
// This is the stable optimum of this structure.
// ---------------------------------------------------------------------------
#define MSG_STRIDE 168   // halves; 131 used + zero pad to 160 (validated)
#define HST        264   // halves; 256 used + 8 pad (validated)

template <int XBF>
__global__ __launch_bounds__(512, 4) void sa_kernel_t(
    const float* __restrict__ x,
    const unsigned short* __restrict__ xbf,
    const float* __restrict__ pos,
    const unsigned short* __restrict__ idx,
    const unsigned char*  __restrict__ cnt,
    const unsigned short* __restrict__ w1s,
    const unsigned short* __restrict__ w2s,
    const float* __restrict__ b1,
    const float* __restrict__ b2,
    float* __restrict__ out)
{
    __shared__ __align__(16) unsigned short msg[128 * MSG_STRIDE];  // 43 KB
    __shared__ __align__(16) __bf16 hsh[64 * HST];                  // 33.8 KB

    const int tid   = threadIdx.x;
    const int pbase = blockIdx.x * 4;
    const int cb    = (pbase >> 11) << 11;          // all 4 points same cloud

    // ---- gather: msg[row][0..127]=bf16(x_j), [128..130]=rel, [131..159]=0
    #pragma unroll
    for (int it = 0; it < 4; ++it) {
        const int task  = it * 512 + tid;           // 0..2047
        const int r     = task >> 4;                // row 0..127
        const int sg    = task & 15;                // 8-elem segment
        const int point = pbase + (r >> 5);
        const int slot  = r & 31;
        const int j     = idx[point * KNB + slot];
        uint4 v;
        if (XBF) {
            v = *reinterpret_cast<const uint4*>(xbf + (size_t)(cb + j) * DINF + sg * 8);
        } else {
            const float* xf = x + (size_t)(cb + j) * DINF + sg * 8;
            const float4 pa = reinterpret_cast<const float4*>(xf)[0];
            const float4 pb = reinterpret_cast<const float4*>(xf)[1];
            v.x = (unsigned int)bf16bits(pa.x) | ((unsigned int)bf16bits(pa.y) << 16);
            v.y = (unsigned int)bf16bits(pa.z) | ((unsigned int)bf16bits(pa.w) << 16);
            v.z = (unsigned int)bf16bits(pb.x) | ((unsigned int)bf16bits(pb.y) << 16);
            v.w = (unsigned int)bf16bits(pb.z) | ((unsigned int)bf16bits(pb.w) << 16);
        }
        *reinterpret_cast<uint4*>(&msg[r * MSG_STRIDE + sg * 8]) = v;
    }
    if (tid < 128) {
        const int r     = tid;
        const int point = pbase + (r >> 5);
        const int slot  = r & 31;
        const int j     = idx[point * KNB + slot];
        const float rx = pos[(size_t)(cb + j) * 3 + 0] - pos[(size_t)point * 3 + 0];
        const float ry = pos[(size_t)(cb + j) * 3 + 1] - pos[(size_t)point * 3 + 1];
        const float rz = pos[(size_t)(cb + j) * 3 + 2] - pos[(size_t)point * 3 + 2];
        uint4 vr;
        vr.x = (unsigned int)bf16bits(rx) | ((unsigned int)bf16bits(ry) << 16);
        vr.y = (unsigned int)bf16bits(rz);
        vr.z = 0u; vr.w = 0u;
        const uint4 z = make_uint4(0u, 0u, 0u, 0u);
        *reinterpret_cast<uint4*>(&msg[r * MSG_STRIDE + 128]) = vr;
        *reinterpret_cast<uint4*>(&msg[r * MSG_STRIDE + 136]) = z;
        *reinterpret_cast<uint4*>(&msg[r * MSG_STRIDE + 144]) = z;
        *reinterpret_cast<uint4*>(&msg[r * MSG_STRIDE + 152]) = z;
    }

    const int w    = tid >> 6;                      // wave owns cols [w*32,w*32+32)
    const int lane = tid & 63;
    const int quad = lane >> 4;
    const int l15  = lane & 15;

    // ---- W1 B-frags + biases in registers (once, reused both phases)
    bf16x8 wf1[5][2];
    #pragma unroll
    for (int ks = 0; ks < 5; ++ks)
        #pragma unroll
        for (int nt = 0; nt < 2; ++nt)
            wf1[ks][nt] = *reinterpret_cast<const bf16x8*>(
                w1s + (size_t)((ks * 16 + (w * 2 + nt)) * 64 + lane) * 8);
    // swapped-D layout: lane reg rg holds col nbase + quad*4 + rg
    float bb1[2][4];
    #pragma unroll
    for (int nt = 0; nt < 2; ++nt) {
        const float4 bv = *reinterpret_cast<const float4*>(b1 + (w * 2 + nt) * 16 + quad * 4);
        bb1[nt][0] = bv.x; bb1[nt][1] = bv.y; bb1[nt][2] = bv.z; bb1[nt][3] = bv.w;
    }
    float bb2[2];
    #pragma unroll
    for (int nt = 0; nt < 2; ++nt) bb2[nt] = b2[(w * 2 + nt) * 16 + l15];
    int myc[4];
    #pragma unroll
    for (int p = 0; p < 4; ++p) {
        int c = cnt[pbase + p];
        myc[p] = (c > KNB) ? KNB : c;
    }
    __syncthreads();   // gather done

    const f32x4 fz = {0.f, 0.f, 0.f, 0.f};

    for (int ph = 0; ph < 2; ++ph) {
        // ---- layer 1 (half): mt_g = ph*4 + mt, writes hsh rows mt*16+..
        #pragma unroll
        for (int mt = 0; mt < 4; ++mt) {
            f32x4 a1[2] = {fz, fz};
            #pragma unroll
            for (int ks = 0; ks < 5; ++ks) {
                const bf16x8 av = *reinterpret_cast<const bf16x8*>(
                    msg + ((ph * 4 + mt) * 16 + l15) * MSG_STRIDE + ks * 32 + quad * 8);
                #pragma unroll
                for (int nt = 0; nt < 2; ++nt)
                    a1[nt] = __builtin_amdgcn_mfma_f32_16x16x32_bf16(wf1[ks][nt], av, a1[nt], 0, 0, 0);
            }
            // bias+relu+bf16 -> h. D' layout: row(l15)=msg row, reg rg = col quad*4+rg
            #pragma unroll
            for (int nt = 0; nt < 2; ++nt) {
                bf16x4 hv4;
                #pragma unroll
                for (int rg = 0; rg < 4; ++rg)
                    hv4[rg] = (__bf16)fmaxf(a1[nt][rg] + bb1[nt][rg], 0.f);
                *reinterpret_cast<bf16x4*>(
                    &hsh[(mt * 16 + l15) * HST + (w * 2 + nt) * 16 + quad * 4]) = hv4;
            }
        }
        __syncthreads();   // h writes -> h reads

        // ---- layer 2 (half): rows ph*64..ph*64+63, ks-outer
        f32x4 acc2[4][2];
        #pragma unroll
        for (int mt = 0; mt < 4; ++mt)
            #pragma unroll
            for (int nt = 0; nt < 2; ++nt) acc2[mt][nt] = fz;

        #pragma unroll
        for (int ks = 0; ks < 8; ++ks) {
            bf16x8 wf2[2];
            #pragma unroll
            for (int nt = 0; nt < 2; ++nt)
                wf2[nt] = *reinterpret_cast<const bf16x8*>(
                    w2s + (size_t)((ks * 16 + (w * 2 + nt)) * 64 + lane) * 8);
            #pragma unroll
            for (int mt = 0; mt < 4; ++mt) {
                const bf16x8 hv = *reinterpret_cast<const bf16x8*>(
                    hsh + (mt * 16 + l15) * HST + ks * 32 + quad * 8);
                #pragma unroll
                for (int nt = 0; nt < 2; ++nt)
                    acc2[mt][nt] = __builtin_amdgcn_mfma_f32_16x16x32_bf16(hv, wf2[nt], acc2[mt][nt], 0, 0, 0);
            }
        }

        // ---- epilogue (half): points pbase + ph*2 + {0,1}
        #pragma unroll
        for (int nt = 0; nt < 2; ++nt) {
            const int col = (w * 2 + nt) * 16 + l15;
            const float bv = bb2[nt];
            #pragma unroll
            for (int p = 0; p < 2; ++p) {
                const int point = pbase + ph * 2 + p;
                const int mc = myc[ph * 2 + p];
                float m = 0.f;                       // post-relu >= 0; self valid
                #pragma unroll
                for (int hh = 0; hh < 2; ++hh) {
                    const int mt = 2 * p + hh;
                    #pragma unroll
                    for (int rg = 0; rg < 4; ++rg) {
                        const int slot = hh * 16 + quad * 4 + rg;
                        const float v = fmaxf(acc2[mt][nt][rg] + bv, 0.f);
                        if (slot < mc) m = fmaxf(m, v);
                    }
                }
                m = fmaxf(m, __shfl_xor(m, 16, 64));
                m = fmaxf(m, __shfl_xor(m, 32, 64));
                if (lane < 16) out[(size_t)point * DOUTF + col] = m;
            }
        }
        __syncthreads();   // hsh reads done before next phase's writes
    }
}

extern "C" void kernel_launch(void* const* d_in, const int* in_sizes, int n_in,
                              void* d_out, int out_size, void* d_ws, size_t ws_size,
                              hipStream_t stream)
{
    const float *x = nullptr, *pos = nullptr, *W1 = nullptr, *W2 = nullptr;
    const float *b1 = nullptr, *b2 = nullptr;
    int nbias = 0;
    for (int i = 0; i < n_in && i < 16; ++i) {
        switch (in_sizes[i]) {
            case NPTS * DINF: x   = (const float*)d_in[i]; break;
            case NPTS * 3:    pos = (const float*)d_in[i]; break;
            case 131 * HID:   W1  = (const float*)d_in[i]; break;
            case HID * DOUTF: W2  = (const float*)d_in[i]; break;
            case 256:         if (nbias == 0) b1 = (const float*)d_in[i];
                              else            b2 = (const float*)d_in[i];
                              ++nbias; break;
            default: break;   // batch (unused; structurally i>>11)
        }
    }
    if (!x)   x   = (const float*)d_in[0];
    if (!pos) pos = (const float*)d_in[1];
    if (!W1)  W1  = (const float*)d_in[3];
    if (!b1)  b1  = (const float*)d_in[4];
    if (!W2)  W2  = (const float*)d_in[5];
    if (!b2)  b2  = (const float*)d_in[6];

    char* ws = (char*)d_ws;
    unsigned short* idx = (unsigned short*)(ws + 0);
    unsigned char*  cnt = (unsigned char*)(ws + 1048576);
    unsigned short* w1s = (unsigned short*)(ws + 1064960);
    unsigned short* w2s = (unsigned short*)(ws + 1146880);
    unsigned short* xbf = (unsigned short*)(ws + WS_XBF_OFF);

    const int use_xbf = (ws_size >= (size_t)WS_XBF_END) ? 1 : 0;
    const int do_tail = (out_size >= NPTS * DOUTF + NPTS * 3 + NPTS) ? 1 : 0;

    float* out    = (float*)d_out;
    float* outpos = out + (size_t)NPTS * DOUTF;
    float* outbat = outpos + (size_t)NPTS * 3;

    hipLaunchKernelGGL(pre_kernel, dim3(256 + 666), dim3(512), 0, stream,
                       pos, x, W1, W2, idx, cnt, w1s, w2s, xbf,
                       outpos, outbat, do_tail, use_xbf);
    if (use_xbf) {
        hipLaunchKernelGGL((sa_kernel_t<1>), dim3(NPTS / 4), dim3(512), 0, stream,
                           x, xbf, pos, idx, cnt, w1s, w2s, b1, b2, out);
    } else {
        hipLaunchKernelGGL((sa_kernel_t<0>), dim3(NPTS / 4), dim3(512), 0, stream,
                           x, xbf, pos, idx, cnt, w1s, w2s, b1, b2, out);
    }
}

// Round 19
// 201.236 us; speedup vs baseline: 1.8050x; 1.0120x over previous
//
#include <hip/hip_runtime.h>
#include <hip/hip_bf16.h>

#define NPTS   16384
#define PPC    2048
#define DINF   128
#define KNB    32
#define HID    256
#define DOUTF  256

typedef __bf16 bf16x8 __attribute__((ext_vector_type(8)));
typedef __bf16 bf16x4 __attribute__((ext_vector_type(4)));
typedef float  f32x4  __attribute__((ext_vector_type(4)));

// ---- ws layout (bytes) ----
// [0,       1048576) : neighbor idx  ushort [NPTS][32]  (cloud-local j)
// [1048576, 1064960) : neighbor cnt  uchar  [NPTS]
// [1064960, 1146880) : W1 swizzled   bf16   [5][16][64][8]
// [1146880, 1277952) : W2 swizzled   bf16   [8][16][64][8]
// [1277952, 5472256) : x bf16 [NPTS][128]
#define WS_XBF_OFF   1277952
#define WS_XBF_END   5472256

static __device__ __forceinline__ unsigned short bf16bits(float f) {
    __hip_bfloat16 h = __float2bfloat16(f);
    return *reinterpret_cast<unsigned short*>(&h);
}

// ---------------------------------------------------------------------------
// Kernel 1 (R31): FUSED pre-kernel = ball-query (blocks 0..255) + aux
// (blocks 256..921). ONE change vs the R26 champion: the per-point merge
// is parallelized via a capped prefix-sum over segment counts — thread
// (p = tid>>3, s = tid&7) writes seg-s entries at op[base_s + r] iff
// base_s + r < 32, where base_s = sum of scnt[0..s-1][p]. This reproduces
// "first 32 of concat(seg0..seg7)" (segs ascending, within-seg ascending =
// the R13-validated order) EXACTLY, with 8 active waves instead of 1 and
// an 8x shorter dependent chain. Thread s==7 writes cnt + zero-fill.
// ---------------------------------------------------------------------------
__global__ __launch_bounds__(512) void pre_kernel(
    const float* __restrict__ pos,
    const float* __restrict__ x,
    const float* __restrict__ W1, const float* __restrict__ W2,
    unsigned short* __restrict__ idx,
    unsigned char* __restrict__ cnt,
    unsigned short* __restrict__ w1s, unsigned short* __restrict__ w2s,
    unsigned short* __restrict__ xbf,
    float* __restrict__ outpos, float* __restrict__ outbat,
    int do_tail, int do_xbf)
{
    __shared__ __align__(16) float4 sp[PPC];              // 32 KB
    __shared__ unsigned short lists[8][64][KNB];          // 32 KB
    __shared__ unsigned char  scnt[8][64];

    const int tid = threadIdx.x;

    if (blockIdx.x < 256) {
        // ---- neigh half (R13-validated semantics: descending-dot, no FMA,
        // d2 = (n2i+n2j)-2*dot <= 0.04f, first-32-ascending-index)
        const int p0  = blockIdx.x * 64;
        const int cb  = (p0 / PPC) * PPC;

        for (int t = tid; t < PPC; t += 512) {
            const float xx = pos[(size_t)(cb + t) * 3 + 0];
            const float yy = pos[(size_t)(cb + t) * 3 + 1];
            const float zz = pos[(size_t)(cb + t) * 3 + 2];
            const float n2 = __fadd_rn(__fadd_rn(__fmul_rn(xx, xx), __fmul_rn(yy, yy)), __fmul_rn(zz, zz));
            sp[t] = make_float4(xx, yy, zz, n2);
        }
        __syncthreads();

        const int seg = tid >> 6;                 // 0..7
        const int p   = tid & 63;
        const float4 pi = sp[p0 - cb + p];

        int c = 0;
        const int jb = seg * (PPC / 8);
        for (int jj = 0; jj < PPC / 8; ++jj) {
            const int j = jb + jj;
            const float4 pj = sp[j];
            const float dot = __fadd_rn(__fadd_rn(__fmul_rn(pi.z, pj.z), __fmul_rn(pi.y, pj.y)),
                                        __fmul_rn(pi.x, pj.x));   // descending (R13-validated)
            const float d2  = __fsub_rn(__fadd_rn(pi.w, pj.w), __fmul_rn(2.0f, dot));
            if (d2 <= 0.04f && c < KNB) { lists[seg][p][c] = (unsigned short)j; ++c; }
        }
        scnt[seg][p] = (unsigned char)c;
        __syncthreads();

        // ---- parallel capped-prefix merge (8 threads per point)
        {
            const int mp = tid >> 3;              // point-lane 0..63
            const int s  = tid & 7;               // segment 0..7
            const int point = p0 + mp;
            unsigned short* op = idx + (size_t)point * KNB;
            int base = 0;
            for (int t = 0; t < s; ++t) base += scnt[t][mp];
            const int cc = scnt[s][mp];
            for (int r = 0; r < cc; ++r) {
                const int k = base + r;
                if (k < KNB) op[k] = lists[s][mp][r];
            }
            if (s == 7) {
                int total = base + cc;
                int k = (total > KNB) ? KNB : total;
                cnt[point] = (unsigned char)k;
                for (; k < KNB; ++k) op[k] = 0;
            }
        }
        return;
    }

    // ---- aux half: gid over [0, 340992)
    const int gid = (blockIdx.x - 256) * 512 + tid;
    if (gid < 5 * 1024) {
        const int ks = gid >> 10, rem = gid & 1023, nt = rem >> 6, lane = rem & 63;
        const int n  = nt * 16 + (lane & 15);
        const int k0 = ks * 32 + ((lane >> 4) * 8);
        unsigned int u[4];
        #pragma unroll
        for (int q = 0; q < 4; ++q) {
            const int ka = k0 + 2 * q, kb = ka + 1;
            const unsigned int lo = (ka < 131) ? (unsigned int)bf16bits(W1[(size_t)ka * HID + n]) : 0u;
            const unsigned int hi = (kb < 131) ? (unsigned int)bf16bits(W1[(size_t)kb * HID + n]) : 0u;
            u[q] = lo | (hi << 16);
        }
        reinterpret_cast<uint4*>(w1s)[gid] = make_uint4(u[0], u[1], u[2], u[3]);
    } else if (gid < 13312) {
        const int t  = gid - 5120;
        const int ks = t >> 10, rem = t & 1023, nt = rem >> 6, lane = rem & 63;
        const int n  = nt * 16 + (lane & 15);
        const int k0 = ks * 32 + ((lane >> 4) * 8);
        unsigned int u[4];
        #pragma unroll
        for (int q = 0; q < 4; ++q) {
            const unsigned int lo = (unsigned int)bf16bits(W2[(size_t)(k0 + 2 * q) * DOUTF + n]);
            const unsigned int hi = (unsigned int)bf16bits(W2[(size_t)(k0 + 2 * q + 1) * DOUTF + n]);
            u[q] = lo | (hi << 16);
        }
        reinterpret_cast<uint4*>(w2s)[t] = make_uint4(u[0], u[1], u[2], u[3]);
    } else if (gid < 13312 + NPTS * 3) {
        if (do_tail) { const int t = gid - 13312; outpos[t] = pos[t]; }
    } else if (gid < 13312 + NPTS * 3 + NPTS) {
        if (do_tail) { const int t = gid - (13312 + NPTS * 3); outbat[t] = (float)(t >> 11); }
    } else {
        const int t = gid - (13312 + NPTS * 3 + NPTS);       // 0..262143
        if (do_xbf && t < NPTS * DINF / 8) {
            const float4 a = reinterpret_cast<const float4*>(x)[t * 2];
            const float4 b = reinterpret_cast<const float4*>(x)[t * 2 + 1];
            uint4 v;
            v.x = (unsigned int)bf16bits(a.x) | ((unsigned int)bf16bits(a.y) << 16);
            v.y = (unsigned int)bf16bits(a.z) | ((unsigned int)bf16bits(a.w) << 16);
            v.z = (unsigned int)bf16bits(b.x) | ((unsigned int)bf16bits(b.y) << 16);
            v.w = (unsigned int)bf16bits(b.z) | ((unsigned int)bf16bits(b.w) << 16);
            reinterpret_cast<uint4*>(xbf)[t] = v;
        }
    }
}

// ---------------------------------------------------------------------------
// Kernel 2 (EXACT R26/R29 champion sa; measured 117.5-119.6us, absmax
// 0.0234, 64 VGPR, no scratch). Design space fully explored and closed:
// nt=4 (4x spill), LDS-shrink (wrong answer / spill-by-bound), smaller
// blocks (weight re-streaming), y-hoist (gather traffic), async-stage
// (+8 VGPR spill), cooperative fusion (spill + L2 loss). Stable optimum.
// ---------------------------------------------------------------------------
#define MSG_STRIDE 168   // halves; 131 used + zero pad to 160 (validated)
#define HST        264   // halves; 256 used + 8 pad (validated)

template <int XBF>
__global__ __launch_bounds__(512, 4) void sa_kernel_t(
    const float* __restrict__ x,
    const unsigned short* __restrict__ xbf,
    const float* __restrict__ pos,
    const unsigned short* __restrict__ idx,
    const unsigned char*  __restrict__ cnt,
    const unsigned short* __restrict__ w1s,
    const unsigned short* __restrict__ w2s,
    const float* __restrict__ b1,
    const float* __restrict__ b2,
    float* __restrict__ out)
{
    __shared__ __align__(16) unsigned short msg[128 * MSG_STRIDE];  // 43 KB
    __shared__ __align__(16) __bf16 hsh[64 * HST];                  // 33.8 KB

    const int tid   = threadIdx.x;
    const int pbase = blockIdx.x * 4;
    const int cb    = (pbase >> 11) << 11;          // all 4 points same cloud

    // ---- gather: msg[row][0..127]=bf16(x_j), [128..130]=rel, [131..159]=0
    #pragma unroll
    for (int it = 0; it < 4; ++it) {
        const int task  = it * 512 + tid;           // 0..2047
        const int r     = task >> 4;                // row 0..127
        const int sg    = task & 15;                // 8-elem segment
        const int point = pbase + (r >> 5);
        const int slot  = r & 31;
        const int j     = idx[point * KNB + slot];
        uint4 v;
        if (XBF) {
            v = *reinterpret_cast<const uint4*>(xbf + (size_t)(cb + j) * DINF + sg * 8);
        } else {
            const float* xf = x + (size_t)(cb + j) * DINF + sg * 8;
            const float4 pa = reinterpret_cast<const float4*>(xf)[0];
            const float4 pb = reinterpret_cast<const float4*>(xf)[1];
            v.x = (unsigned int)bf16bits(pa.x) | ((unsigned int)bf16bits(pa.y) << 16);
            v.y = (unsigned int)bf16bits(pa.z) | ((unsigned int)bf16bits(pa.w) << 16);
            v.z = (unsigned int)bf16bits(pb.x) | ((unsigned int)bf16bits(pb.y) << 16);
            v.w = (unsigned int)bf16bits(pb.z) | ((unsigned int)bf16bits(pb.w) << 16);
        }
        *reinterpret_cast<uint4*>(&msg[r * MSG_STRIDE + sg * 8]) = v;
    }
    if (tid < 128) {
        const int r     = tid;
        const int point = pbase + (r >> 5);
        const int slot  = r & 31;
        const int j     = idx[point * KNB + slot];
        const float rx = pos[(size_t)(cb + j) * 3 + 0] - pos[(size_t)point * 3 + 0];
        const float ry = pos[(size_t)(cb + j) * 3 + 1] - pos[(size_t)point * 3 + 1];
        const float rz = pos[(size_t)(cb + j) * 3 + 2] - pos[(size_t)point * 3 + 2];
        uint4 vr;
        vr.x = (unsigned int)bf16bits(rx) | ((unsigned int)bf16bits(ry) << 16);
        vr.y = (unsigned int)bf16bits(rz);
        vr.z = 0u; vr.w = 0u;
        const uint4 z = make_uint4(0u, 0u, 0u, 0u);
        *reinterpret_cast<uint4*>(&msg[r * MSG_STRIDE + 128]) = vr;
        *reinterpret_cast<uint4*>(&msg[r * MSG_STRIDE + 136]) = z;
        *reinterpret_cast<uint4*>(&msg[r * MSG_STRIDE + 144]) = z;
        *reinterpret_cast<uint4*>(&msg[r * MSG_STRIDE + 152]) = z;
    }

    const int w    = tid >> 6;                      // wave owns cols [w*32,w*32+32)
    const int lane = tid & 63;
    const int quad = lane >> 4;
    const int l15  = lane & 15;

    // ---- W1 B-frags + biases in registers (once, reused both phases)
    bf16x8 wf1[5][2];
    #pragma unroll
    for (int ks = 0; ks < 5; ++ks)
        #pragma unroll
        for (int nt = 0; nt < 2; ++nt)
            wf1[ks][nt] = *reinterpret_cast<const bf16x8*>(
                w1s + (size_t)((ks * 16 + (w * 2 + nt)) * 64 + lane) * 8);
    // swapped-D layout: lane reg rg holds col nbase + quad*4 + rg
    float bb1[2][4];
    #pragma unroll
    for (int nt = 0; nt < 2; ++nt) {
        const float4 bv = *reinterpret_cast<const float4*>(b1 + (w * 2 + nt) * 16 + quad * 4);
        bb1[nt][0] = bv.x; bb1[nt][1] = bv.y; bb1[nt][2] = bv.z; bb1[nt][3] = bv.w;
    }
    float bb2[2];
    #pragma unroll
    for (int nt = 0; nt < 2; ++nt) bb2[nt] = b2[(w * 2 + nt) * 16 + l15];
    int myc[4];
    #pragma unroll
    for (int p = 0; p < 4; ++p) {
        int c = cnt[pbase + p];
        myc[p] = (c > KNB) ? KNB : c;
    }
    __syncthreads();   // gather done

    const f32x4 fz = {0.f, 0.f, 0.f, 0.f};

    for (int ph = 0; ph < 2; ++ph) {
        // ---- layer 1 (half): mt_g = ph*4 + mt, writes hsh rows mt*16+..
        #pragma unroll
        for (int mt = 0; mt < 4; ++mt) {
            f32x4 a1[2] = {fz, fz};
            #pragma unroll
            for (int ks = 0; ks < 5; ++ks) {
                const bf16x8 av = *reinterpret_cast<const bf16x8*>(
                    msg + ((ph * 4 + mt) * 16 + l15) * MSG_STRIDE + ks * 32 + quad * 8);
                #pragma unroll
                for (int nt = 0; nt < 2; ++nt)
                    a1[nt] = __builtin_amdgcn_mfma_f32_16x16x32_bf16(wf1[ks][nt], av, a1[nt], 0, 0, 0);
            }
            // bias+relu+bf16 -> h. D' layout: row(l15)=msg row, reg rg = col quad*4+rg
            #pragma unroll
            for (int nt = 0; nt < 2; ++nt) {
                bf16x4 hv4;
                #pragma unroll
                for (int rg = 0; rg < 4; ++rg)
                    hv4[rg] = (__bf16)fmaxf(a1[nt][rg] + bb1[nt][rg], 0.f);
                *reinterpret_cast<bf16x4*>(
                    &hsh[(mt * 16 + l15) * HST + (w * 2 + nt) * 16 + quad * 4]) = hv4;
            }
        }
        __syncthreads();   // h writes -> h reads

        // ---- layer 2 (half): rows ph*64..ph*64+63, ks-outer
        f32x4 acc2[4][2];
        #pragma unroll
        for (int mt = 0; mt < 4; ++mt)
            #pragma unroll
            for (int nt = 0; nt < 2; ++nt) acc2[mt][nt] = fz;

        #pragma unroll
        for (int ks = 0; ks < 8; ++ks) {
            bf16x8 wf2[2];
            #pragma unroll
            for (int nt = 0; nt < 2; ++nt)
                wf2[nt] = *reinterpret_cast<const bf16x8*>(
                    w2s + (size_t)((ks * 16 + (w * 2 + nt)) * 64 + lane) * 8);
            #pragma unroll
            for (int mt = 0; mt < 4; ++mt) {
                const bf16x8 hv = *reinterpret_cast<const bf16x8*>(
                    hsh + (mt * 16 + l15) * HST + ks * 32 + quad * 8);
                #pragma unroll
                for (int nt = 0; nt < 2; ++nt)
                    acc2[mt][nt] = __builtin_amdgcn_mfma_f32_16x16x32_bf16(hv, wf2[nt], acc2[mt][nt], 0, 0, 0);
            }
        }

        // ---- epilogue (half): points pbase + ph*2 + {0,1}
        #pragma unroll
        for (int nt = 0; nt < 2; ++nt) {
            const int col = (w * 2 + nt) * 16 + l15;
            const float bv = bb2[nt];
            #pragma unroll
            for (int p = 0; p < 2; ++p) {
                const int point = pbase + ph * 2 + p;
                const int mc = myc[ph * 2 + p];
                float m = 0.f;                       // post-relu >= 0; self valid
                #pragma unroll
                for (int hh = 0; hh < 2; ++hh) {
                    const int mt = 2 * p + hh;
                    #pragma unroll
                    for (int rg = 0; rg < 4; ++rg) {
                        const int slot = hh * 16 + quad * 4 + rg;
                        const float v = fmaxf(acc2[mt][nt][rg] + bv, 0.f);
                        if (slot < mc) m = fmaxf(m, v);
                    }
                }
                m = fmaxf(m, __shfl_xor(m, 16, 64));
                m = fmaxf(m, __shfl_xor(m, 32, 64));
                if (lane < 16) out[(size_t)point * DOUTF + col] = m;
            }
        }
        __syncthreads();   // hsh reads done before next phase's writes
    }
}

extern "C" void kernel_launch(void* const* d_in, const int* in_sizes, int n_in,
                              void* d_out, int out_size, void* d_ws, size_t ws_size,
                              hipStream_t stream)
{
    const float *x = nullptr, *pos = nullptr, *W1 = nullptr, *W2 = nullptr;
    const float *b1 = nullptr, *b2 = nullptr;
    int nbias = 0;
    for (int i = 0; i < n_in && i < 16; ++i) {
        switch (in_sizes[i]) {
            case NPTS * DINF: x   = (const float*)d_in[i]; break;
            case NPTS * 3:    pos = (const float*)d_in[i]; break;
            case 131 * HID:   W1  = (const float*)d_in[i]; break;
            case HID * DOUTF: W2  = (const float*)d_in[i]; break;
            case 256:         if (nbias == 0) b1 = (const float*)d_in[i];
                              else            b2 = (const float*)d_in[i];
                              ++nbias; break;
            default: break;   // batch (unused; structurally i>>11)
        }
    }
    if (!x)   x   = (const float*)d_in[0];
    if (!pos) pos = (const float*)d_in[1];
    if (!W1)  W1  = (const float*)d_in[3];
    if (!b1)  b1  = (const float*)d_in[4];
    if (!W2)  W2  = (const float*)d_in[5];
    if (!b2)  b2  = (const float*)d_in[6];

    char* ws = (char*)d_ws;
    unsigned short* idx = (unsigned short*)(ws + 0);
    unsigned char*  cnt = (unsigned char*)(ws + 1048576);
    unsigned short* w1s = (unsigned short*)(ws + 1064960);
    unsigned short* w2s = (unsigned short*)(ws + 1146880);
    unsigned short* xbf = (unsigned short*)(ws + WS_XBF_OFF);

    const int use_xbf = (ws_size >= (size_t)WS_XBF_END) ? 1 : 0;
    const int do_tail = (out_size >= NPTS * DOUTF + NPTS * 3 + NPTS) ? 1 : 0;

    float* out    = (float*)d_out;
    float* outpos = out + (size_t)NPTS * DOUTF;
    float* outbat = outpos + (size_t)NPTS * 3;

    hipLaunchKernelGGL(pre_kernel, dim3(256 + 666), dim3(512), 0, stream,
                       pos, x, W1, W2, idx, cnt, w1s, w2s, xbf,
                       outpos, outbat, do_tail, use_xbf);
    if (use_xbf) {
        hipLaunchKernelGGL((sa_kernel_t<1>), dim3(NPTS / 4), dim3(512), 0, stream,
                           x, xbf, pos, idx, cnt, w1s, w2s, b1, b2, out);
    } else {
        hipLaunchKernelGGL((sa_kernel_t<0>), dim3(NPTS / 4), dim3(512), 0, stream,
                           x, xbf, pos, idx, cnt, w1s, w2s, b1, b2, out);
    }
}